// Round 8
// baseline (82.308 us; speedup 1.0000x reference)
//
#include <hip/hip_runtime.h>

// LinearAttention fp32 [4,16,4096,64]: out = (Q' (K'^T V)) / (Q'.k_sum + eps), X' = elu(X)+1.
// Pass 1 (kv_mfma): SINGLE-PHASE blocks — 2048 blocks, 128 s-rows each: issue all
//   16 float4 loads, elu/pack bf16 transposed into LDS (conflict-free XOR swizzle),
//   ONE barrier, 16x mfma_f32_16x16x32_bf16, store partial, exit. Latency is paid
//   once per block; overlap comes from 4 resident blocks/CU + continuous block
//   retire/launch stagger (no intra-block lockstep phases for barriers to drain).
// Pass 1b (reduce_partials): fold NPB partials per bh.
// Pass 2 (out_kernel): unchanged (~HBM roofline).

#define EPS_LA 1e-6f

constexpr int BH = 64;
constexpr int SEQ = 4096;
constexpr int DIM = 64;
constexpr int KVELEM = DIM * DIM + DIM;  // 4160
constexpr int NPB = 32;                  // partial blocks per bh
constexpr int SCH = SEQ / NPB;           // 128 s-rows per block

typedef short bf16x8 __attribute__((ext_vector_type(8)));
typedef float f32x4 __attribute__((ext_vector_type(4)));

__device__ __forceinline__ float elu1(float x) {
    return x > 0.f ? x + 1.f : __expf(x);
}
__device__ __forceinline__ void elu4(float4& v) {
    v.x = elu1(v.x); v.y = elu1(v.y); v.z = elu1(v.z); v.w = elu1(v.w);
}

// fp32 -> bf16 (RNE; inputs finite)
__device__ __forceinline__ unsigned int f2bf(float x) {
    unsigned int u = __float_as_uint(x);
    return (u + 0x7fffu + ((u >> 16) & 1u)) >> 16;
}
__device__ __forceinline__ unsigned int pack2bf(float lo, float hi) {
    return f2bf(lo) | (f2bf(hi) << 16);
}

// Dword index into KT/VT[64 d-rows][64 s-pairs]. XOR of ((d>>1)^(d>>2))&7 into
// s2 bits 2..4: staging b32 writes land 2 lanes/bank (free); MFMA b128 reads at
// the b128 minimum. Preserves 16B alignment (bits 0..1 untouched).
__device__ __forceinline__ int swz(int d, int s2) {
    return d * 64 + (s2 ^ ((((d >> 1) ^ (d >> 2)) & 7) << 2));
}

template<bool ATOMIC>
__global__ __launch_bounds__(256, 4) void kv_mfma_kernel(
    const float* __restrict__ K, const float* __restrict__ V,
    float* __restrict__ dst) {
    const int bh = blockIdx.y;
    const int blk = blockIdx.x;
    const int t = threadIdx.x;
    const int w = t >> 6, l = t & 63;

    __shared__ unsigned int KT[64 * 64];  // 16 KB: K'^T bf16 [d][s-pair] swizzled
    __shared__ unsigned int VT[64 * 64];  // 16 KB
    __shared__ float csumS[4][64];        // 1 KB

    const float* Kb = K + ((size_t)bh * SEQ + (size_t)blk * SCH) * DIM;
    const float* Vb = V + ((size_t)bh * SEQ + (size_t)blk * SCH) * DIM;

    const int c0 = (t & 15) * 4;  // staged col base (d rows c0..c0+3)
    const int pg = t >> 4;        // s-pair group base: pairs pg, pg+16, pg+32, pg+48
    const int lg = l >> 4;        // MFMA k-slice group 0..3
    const int lr = l & 15;        // MFMA row/col within tile

    // ---- issue ALL loads up-front (16 outstanding float4s per thread) ----
    float4 kf[8], vf[8];
    #pragma unroll
    for (int i = 0; i < 4; ++i) {
        const int p = pg + 16 * i;
        const float* Ks = Kb + (size_t)(2 * p) * DIM + c0;
        kf[2 * i]     = *(const float4*)Ks;
        kf[2 * i + 1] = *(const float4*)(Ks + DIM);
    }
    #pragma unroll
    for (int i = 0; i < 4; ++i) {
        const int p = pg + 16 * i;
        const float* Vs = Vb + (size_t)(2 * p) * DIM + c0;
        vf[2 * i]     = *(const float4*)Vs;
        vf[2 * i + 1] = *(const float4*)(Vs + DIM);
    }

    // ---- elu + pack + transpose into LDS ----
    float cs0 = 0.f, cs1 = 0.f, cs2 = 0.f, cs3 = 0.f;
    #pragma unroll
    for (int i = 0; i < 4; ++i) {
        const int p = pg + 16 * i;
        float4 ka = kf[2 * i], kb = kf[2 * i + 1];
        elu4(ka); elu4(kb);
        cs0 += ka.x + kb.x; cs1 += ka.y + kb.y;
        cs2 += ka.z + kb.z; cs3 += ka.w + kb.w;
        KT[swz(c0 + 0, p)] = pack2bf(ka.x, kb.x);
        KT[swz(c0 + 1, p)] = pack2bf(ka.y, kb.y);
        KT[swz(c0 + 2, p)] = pack2bf(ka.z, kb.z);
        KT[swz(c0 + 3, p)] = pack2bf(ka.w, kb.w);
        const float4 va = vf[2 * i], vb = vf[2 * i + 1];
        VT[swz(c0 + 0, p)] = pack2bf(va.x, vb.x);
        VT[swz(c0 + 1, p)] = pack2bf(va.y, vb.y);
        VT[swz(c0 + 2, p)] = pack2bf(va.z, vb.z);
        VT[swz(c0 + 3, p)] = pack2bf(va.w, vb.w);
    }

    // fold column sums across 16-lane groups (lanes l, l^16, l^32, l^48 share c0)
    cs0 += __shfl_xor(cs0, 16); cs0 += __shfl_xor(cs0, 32);
    cs1 += __shfl_xor(cs1, 16); cs1 += __shfl_xor(cs1, 32);
    cs2 += __shfl_xor(cs2, 16); cs2 += __shfl_xor(cs2, 32);
    cs3 += __shfl_xor(cs3, 16); cs3 += __shfl_xor(cs3, 32);
    if (l < 16) *(float4*)&csumS[w][l * 4] = make_float4(cs0, cs1, cs2, cs3);

    __syncthreads();  // the ONLY barrier

    // ---- MFMA: wave w owns e-cols [16w,16w+16); K=128 (4 steps of 32) ----
    f32x4 acc[4];
    #pragma unroll
    for (int m = 0; m < 4; ++m)
        #pragma unroll
        for (int r = 0; r < 4; ++r) acc[m][r] = 0.f;

    #pragma unroll
    for (int ks = 0; ks < 4; ++ks) {
        const int s2b = ks * 16 + lg * 4;  // 16B-aligned dword base of k-slice
        const bf16x8 bfrag =
            *reinterpret_cast<const bf16x8*>(&VT[swz(16 * w + lr, s2b)]);
        #pragma unroll
        for (int m = 0; m < 4; ++m) {
            const bf16x8 afrag =
                *reinterpret_cast<const bf16x8*>(&KT[swz(16 * m + lr, s2b)]);
            acc[m] = __builtin_amdgcn_mfma_f32_16x16x32_bf16(afrag, bfrag, acc[m],
                                                             0, 0, 0);
        }
    }

    float* wout = ATOMIC ? dst + (size_t)bh * KVELEM
                         : dst + ((size_t)blk * BH + bh) * KVELEM;

    // ksum: fold the 4 wave partials (visible since the barrier)
    if (t < 64) {
        const float s = csumS[0][t] + csumS[1][t] + csumS[2][t] + csumS[3][t];
        if (ATOMIC) atomicAdd(&wout[DIM * DIM + t], s);
        else        wout[DIM * DIM + t] = s;
    }

    // store D: tile m -> rows d=16m+4lg+r, col e=16w+lr
    #pragma unroll
    for (int m = 0; m < 4; ++m) {
        #pragma unroll
        for (int r = 0; r < 4; ++r) {
            const int d = 16 * m + 4 * lg + r;
            const int e = 16 * w + lr;
            if (ATOMIC) atomicAdd(&wout[(size_t)d * DIM + e], acc[m][r]);
            else        wout[(size_t)d * DIM + e] = acc[m][r];
        }
    }
}

__global__ __launch_bounds__(256) void reduce_partials_kernel(
    const float* __restrict__ partial, float* __restrict__ fin) {
    const int bh = blockIdx.y;
    const int j = blockIdx.x * 256 + threadIdx.x;
    if (j >= KVELEM) return;
    float s = 0.f;
    #pragma unroll
    for (int c = 0; c < NPB; ++c)
        s += partial[((size_t)c * BH + bh) * KVELEM + j];
    fin[(size_t)bh * KVELEM + j] = s;
}

// Pass 2: block = 256 thr (4 waves), 128 q-rows/block (32/wave). Thread tile 4x8.
// (Measured ~HBM roofline; unchanged.)
__global__ __launch_bounds__(256) void out_kernel(
    const float* __restrict__ Q, const float* __restrict__ ws,
    float* __restrict__ out) {
    const int bh = blockIdx.y;
    const int rb = blockIdx.x;  // 128-row block
    const int wave = threadIdx.x >> 6, lane = threadIdx.x & 63;
    const int t = threadIdx.x;
    const int tr = lane >> 3;   // 0..7 -> rows 4tr..4tr+3 (within wave's 32)
    const int tc = lane & 7;    // 0..7 -> cols 8tc..8tc+7

    const float* w = ws + (size_t)bh * KVELEM;
    const float* Qw = Q + ((size_t)bh * SEQ + (size_t)rb * 128 + (size_t)wave * 32) * DIM;
    float* Ow = out + ((size_t)bh * SEQ + (size_t)rb * 128 + (size_t)wave * 32) * DIM;

    __shared__ float kvS[DIM][DIM];    // 16 KB
    __shared__ float ksumS[DIM];
    __shared__ float qS[4][32][DIM];   // 32 KB, per-wave, XOR-swizzled col-chunks

    // cooperative kv load (whole block, 4096 floats)
    #pragma unroll
    for (int i = 0; i < 4; ++i) {
        const int idx = (i * 256 + t) * 4;
        *(float4*)&kvS[idx >> 6][idx & 63] = *(const float4*)(w + idx);
    }
    if (t < DIM) ksumS[t] = w[DIM * DIM + t];

    // per-wave q stage: 32 rows x 64 cols, elu'd; col-chunk cc stored at cc^((row>>2)&7)
    #pragma unroll
    for (int it = 0; it < 8; ++it) {
        const int row = it * 4 + (lane >> 4);   // 0..31
        const int cc = lane & 15;               // col chunk 0..15
        float4 qv = *(const float4*)(Qw + (size_t)row * DIM + cc * 4);
        elu4(qv);
        *(float4*)&qS[wave][row][((cc ^ ((row >> 2) & 7)) & 15) * 4] = qv;
    }
    __syncthreads();

    float acc[4][8] = {{0.f}};
    float accd[4] = {0.f, 0.f, 0.f, 0.f};

    #pragma unroll 2
    for (int dc = 0; dc < 16; ++dc) {  // d-chunks of 4
        float4 qv[4];
        #pragma unroll
        for (int i = 0; i < 4; ++i)
            qv[i] = *(const float4*)&qS[wave][tr * 4 + i][((dc ^ tr) & 15) * 4];
        const float4 ks = *(const float4*)&ksumS[dc * 4];
        #pragma unroll
        for (int dd = 0; dd < 4; ++dd) {
            const int d = dc * 4 + dd;
            const float4 ka = *(const float4*)&kvS[d][tc * 8];
            const float4 kb = *(const float4*)&kvS[d][tc * 8 + 4];
            const float ksd = (&ks.x)[dd];
            #pragma unroll
            for (int i = 0; i < 4; ++i) {
                const float qq = (&qv[i].x)[dd];
                accd[i] += qq * ksd;
                acc[i][0] += qq * ka.x; acc[i][1] += qq * ka.y;
                acc[i][2] += qq * ka.z; acc[i][3] += qq * ka.w;
                acc[i][4] += qq * kb.x; acc[i][5] += qq * kb.y;
                acc[i][6] += qq * kb.z; acc[i][7] += qq * kb.w;
            }
        }
    }

    #pragma unroll
    for (int i = 0; i < 4; ++i) {
        const float inv = 1.f / (accd[i] + EPS_LA);
        float4 o0, o1;
        o0.x = acc[i][0] * inv; o0.y = acc[i][1] * inv;
        o0.z = acc[i][2] * inv; o0.w = acc[i][3] * inv;
        o1.x = acc[i][4] * inv; o1.y = acc[i][5] * inv;
        o1.z = acc[i][6] * inv; o1.w = acc[i][7] * inv;
        float* orow = Ow + (size_t)(tr * 4 + i) * DIM + tc * 8;
        *(float4*)(orow) = o0;
        *(float4*)(orow + 4) = o1;
    }
}

extern "C" void kernel_launch(void* const* d_in, const int* in_sizes, int n_in,
                              void* d_out, int out_size, void* d_ws, size_t ws_size,
                              hipStream_t stream) {
    const float* q = (const float*)d_in[0];
    const float* k = (const float*)d_in[1];
    const float* v = (const float*)d_in[2];
    float* out = (float*)d_out;
    float* ws = (float*)d_ws;

    const size_t partial_elems = (size_t)NPB * BH * KVELEM;
    const size_t need = (partial_elems + (size_t)BH * KVELEM) * sizeof(float);

    dim3 blk(256);
    const float* fin_ptr;
    if (ws_size >= need) {
        float* partial = ws;
        float* fin = ws + partial_elems;
        hipLaunchKernelGGL((kv_mfma_kernel<false>), dim3(NPB, BH), blk, 0, stream,
                           k, v, partial);
        hipLaunchKernelGGL(reduce_partials_kernel, dim3((KVELEM + 255) / 256, BH),
                           blk, 0, stream, partial, fin);
        fin_ptr = fin;
    } else {
        float* fin = ws;
        hipMemsetAsync(fin, 0, (size_t)BH * KVELEM * sizeof(float), stream);
        hipLaunchKernelGGL((kv_mfma_kernel<true>), dim3(NPB, BH), blk, 0, stream,
                           k, v, fin);
        fin_ptr = fin;
    }
    hipLaunchKernelGGL(out_kernel, dim3(SEQ / 128, BH), blk, 0, stream,
                       q, fin_ptr, out);
}